// Round 3
// baseline (366.019 us; speedup 1.0000x reference)
//
#include <hip/hip_runtime.h>
#include <math.h>

// Problem constants
#define BB 8
#define TUU 128
#define THH 512
#define HDIM 512
#define VOC 32000
#define WID_ (VOC + THH)   // 32512

// ws float offsets
#define OFF_GH      0        // 8*1536
#define OFF_BIASATT 12288    // 8*512
#define OFF_CEMB    16384    // 8*512
#define OFF_LATT    20480    // 8*128   (zeroed)
#define OFF_SSUM    21504    // 8       (zeroed, unused now)
#define OFF_SCORE   21568    // 8*512   (zeroed)
#define OFF_EXTRA   25664    // 8*32512 (zeroed)
#define OFF_Y       285760   // 8*1024  (context | h_new)
#define OFF_GI      293952   // 8*1536
#define OFF_PGEN    306240   // 8
#define OFF_M       306248   // 8
#define OFF_EPS     306256   // 8
#define OFF_WSPLIT_BYTES 1225056   // = (306256+8)*4 ; u16 arrays start here
// u16 offsets from OFF_WSPLIT_BYTES: WC_HI 0, WC_LO 262144, WA_HI 524288, WA_LO 786432

#define OUT_H1 260096
#define OUT_H2 264192

#define SM_SHIFT 20.0f

typedef __attribute__((ext_vector_type(8))) short short8;
typedef __attribute__((ext_vector_type(4))) float f32x4;

__device__ __forceinline__ float wave_sum(float v) {
#pragma unroll
    for (int m = 1; m < 64; m <<= 1) v += __shfl_xor(v, m, 64);
    return v;
}

__device__ __forceinline__ unsigned short f2bf(float x) {
    unsigned int u = __float_as_uint(x);
    unsigned int r = (u + 0x7fffu + ((u >> 16) & 1u)) >> 16;
    return (unsigned short)r;
}
__device__ __forceinline__ float bf2f(unsigned short h) {
    return __uint_as_float(((unsigned int)h) << 16);
}

// K1 (fused): blocks 0..1023 split-convert weights; 1024..1535 gh/bias_att GEMVs;
// 1536..1551 c_embed gather. All independent.
__global__ __launch_bounds__(256) void k_pre(
    const float* __restrict__ c2W, const float* __restrict__ attn_W,
    const float* __restrict__ attn_b,
    const float* __restrict__ gru_Whh, const float* __restrict__ gru_bhh,
    const float* __restrict__ emb_W, const int* __restrict__ c_t,
    const float* __restrict__ last_h,
    unsigned short* __restrict__ wbase, float* __restrict__ ws)
{
    int bx = blockIdx.x, tid = threadIdx.x;
    if (bx < 1024) {
        int i = bx * 256 + tid;            // 0..262143
        float x = c2W[i];
        unsigned short h = f2bf(x);
        wbase[i] = h;
        wbase[262144 + i] = f2bf(x - bf2f(h));
        int j = i >> 9, k = i & 511;
        float y = attn_W[(size_t)j * 1024 + 512 + k];
        unsigned short h2 = f2bf(y);
        wbase[524288 + i] = h2;
        wbase[786432 + i] = f2bf(y - bf2f(h2));
    } else if (bx < 1536) {
        int lane = tid & 63;
        int wid = __builtin_amdgcn_readfirstlane((bx - 1024) * 4 + (tid >> 6)); // 0..2047
        const float* wr;
        if (wid < 1536) wr = gru_Whh + (size_t)wid * 512;
        else            wr = attn_W + (size_t)(wid - 1536) * 1024;
        int k = lane * 8;
        float4 w0 = *reinterpret_cast<const float4*>(wr + k);
        float4 w1 = *reinterpret_cast<const float4*>(wr + k + 4);
        float acc[8];
#pragma unroll
        for (int b = 0; b < 8; ++b) {
            const float* hv = last_h + b * 512 + k;
            float4 h0 = *reinterpret_cast<const float4*>(hv);
            float4 h1 = *reinterpret_cast<const float4*>(hv + 4);
            acc[b] = w0.x*h0.x + w0.y*h0.y + w0.z*h0.z + w0.w*h0.w
                   + w1.x*h1.x + w1.y*h1.y + w1.z*h1.z + w1.w*h1.w;
        }
#pragma unroll
        for (int b = 0; b < 8; ++b) acc[b] = wave_sum(acc[b]);
        if (lane == 0) {
            if (wid < 1536) {
                float bias = gru_bhh[wid];
#pragma unroll
                for (int b = 0; b < 8; ++b) ws[OFF_GH + b * 1536 + wid] = acc[b] + bias;
            } else {
                int j = wid - 1536;
                float bias = attn_b[j];
#pragma unroll
                for (int b = 0; b < 8; ++b) ws[OFF_BIASATT + b * 512 + j] = acc[b] + bias;
            }
        }
    } else {
        int idx = (bx - 1536) * 256 + tid;  // 0..4095
        int b = idx >> 9, k = idx & 511;
        ws[OFF_CEMB + idx] = emb_W[(size_t)c_t[b] * 512 + k];
    }
}

// Split-bf16 MFMA tanh-GEMM body (shared by att kernel and fused gemm+proj)
// out[b, t] += sum_j tanh( (A@W^T)[r,j] + bias[b,j] ) * wv[b,j],  r = t*8+b
__device__ __forceinline__ void mfma_tanh_body(
    const float* __restrict__ A,
    const unsigned short* __restrict__ Whi, const unsigned short* __restrict__ Wlo,
    const float* __restrict__ bias, int bstride,
    const float* __restrict__ wvp, int wstride,
    float* __restrict__ outp, int Mout,
    int rbase, int j0,
    short (*As)[64][40], short (*Ws)[128][40])
{
    int tid  = threadIdx.x;
    int lane = tid & 63;
    int wv   = tid >> 6;

    f32x4 acc[4][2];
#pragma unroll
    for (int mt = 0; mt < 4; ++mt)
#pragma unroll
        for (int nt = 0; nt < 2; ++nt) acc[mt][nt] = (f32x4)0.0f;

    int q8  = (lane >> 4) * 8;
    int l15 = lane & 15;
    int ra  = tid >> 2, kk = (tid & 3) * 8;
    int jw  = tid >> 1, kh = (tid & 1) * 16;

    for (int kc = 0; kc < 16; ++kc) {
        int k0 = kc * 32;
        {
            const float* ap = A + (size_t)(rbase + ra) * 512 + k0 + kk;
            float4 a0 = *reinterpret_cast<const float4*>(ap);
            float4 a1 = *reinterpret_cast<const float4*>(ap + 4);
            float vals[8] = {a0.x, a0.y, a0.z, a0.w, a1.x, a1.y, a1.z, a1.w};
            union { short8 v; short s[8]; } hi, lo;
#pragma unroll
            for (int i = 0; i < 8; ++i) {
                unsigned short h = f2bf(vals[i]);
                hi.s[i] = (short)h;
                lo.s[i] = (short)f2bf(vals[i] - bf2f(h));
            }
            *reinterpret_cast<short8*>(&As[0][ra][kk]) = hi.v;
            *reinterpret_cast<short8*>(&As[1][ra][kk]) = lo.v;
        }
        {
            const short8* wph = reinterpret_cast<const short8*>(Whi + (size_t)(j0 + jw) * 512 + k0 + kh);
            const short8* wpl = reinterpret_cast<const short8*>(Wlo + (size_t)(j0 + jw) * 512 + k0 + kh);
            *reinterpret_cast<short8*>(&Ws[0][jw][kh])     = wph[0];
            *reinterpret_cast<short8*>(&Ws[0][jw][kh + 8]) = wph[1];
            *reinterpret_cast<short8*>(&Ws[1][jw][kh])     = wpl[0];
            *reinterpret_cast<short8*>(&Ws[1][jw][kh + 8]) = wpl[1];
        }
        __syncthreads();

        short8 ah[4], al[4], bh[2], bl[2];
#pragma unroll
        for (int mt = 0; mt < 4; ++mt) {
            ah[mt] = *reinterpret_cast<const short8*>(&As[0][mt * 16 + l15][q8]);
            al[mt] = *reinterpret_cast<const short8*>(&As[1][mt * 16 + l15][q8]);
        }
#pragma unroll
        for (int nt = 0; nt < 2; ++nt) {
            bh[nt] = *reinterpret_cast<const short8*>(&Ws[0][wv * 32 + nt * 16 + l15][q8]);
            bl[nt] = *reinterpret_cast<const short8*>(&Ws[1][wv * 32 + nt * 16 + l15][q8]);
        }
#pragma unroll
        for (int mt = 0; mt < 4; ++mt)
#pragma unroll
            for (int nt = 0; nt < 2; ++nt) {
                acc[mt][nt] = __builtin_amdgcn_mfma_f32_16x16x32_bf16(ah[mt], bh[nt], acc[mt][nt], 0, 0, 0);
                acc[mt][nt] = __builtin_amdgcn_mfma_f32_16x16x32_bf16(ah[mt], bl[nt], acc[mt][nt], 0, 0, 0);
                acc[mt][nt] = __builtin_amdgcn_mfma_f32_16x16x32_bf16(al[mt], bh[nt], acc[mt][nt], 0, 0, 0);
            }
        __syncthreads();
    }

    int q = lane >> 4;
#pragma unroll
    for (int mt = 0; mt < 4; ++mt) {
        float s[4];
#pragma unroll
        for (int r = 0; r < 4; ++r) {
            int row = rbase + mt * 16 + q * 4 + r;
            int b = row & 7;
            float v = 0.f;
#pragma unroll
            for (int nt = 0; nt < 2; ++nt) {
                int jj = j0 + wv * 32 + nt * 16 + l15;
                float e = acc[mt][nt][r] + bias[b * bstride + jj];
                v += tanhf(e) * wvp[b * wstride + jj];
            }
#pragma unroll
            for (int m = 1; m < 16; m <<= 1) v += __shfl_xor(v, m, 64);
            s[r] = v;
        }
        if (l15 == 0) {
#pragma unroll
            for (int r = 0; r < 4; ++r) {
                int row = rbase + mt * 16 + q * 4 + r;
                atomicAdd(outp + (row & 7) * Mout + (row >> 3), s[r]);
            }
        }
    }
}

// K2: attention energy GEMM (A = u_enc, 1024 rows)
__global__ __launch_bounds__(256) void k_attgemm(
    const float* __restrict__ A, const unsigned short* __restrict__ wsplit,
    const float* __restrict__ attnv, float* __restrict__ ws)
{
    __shared__ short As[2][64][40];
    __shared__ short Ws[2][128][40];
    mfma_tanh_body(A, wsplit + 524288, wsplit + 786432,
                   ws + OFF_BIASATT, 512, attnv, 0,
                   ws + OFF_LATT, 128,
                   blockIdx.x * 64, blockIdx.y * 128, As, Ws);
}

// K3a: softmax over att logits (Tu=128) + context -> y[:,0:512]
__global__ __launch_bounds__(256) void k_attn_ctx(
    const float* __restrict__ u_enc, float* __restrict__ ws)
{
    __shared__ float red[256];
    __shared__ float att[128];
    int b = blockIdx.x, tid = threadIdx.x;
    float l = (tid < 128) ? ws[OFF_LATT + b * 128 + tid] : -1e30f;
    red[tid] = l; __syncthreads();
    for (int s = 128; s > 0; s >>= 1) {
        if (tid < s) red[tid] = fmaxf(red[tid], red[tid + s]);
        __syncthreads();
    }
    float mm = red[0]; __syncthreads();
    float e = (tid < 128) ? expf(l - mm) : 0.f;
    if (tid < 128) att[tid] = e;
    red[tid] = e; __syncthreads();
    for (int s = 128; s > 0; s >>= 1) {
        if (tid < s) red[tid] += red[tid + s];
        __syncthreads();
    }
    float S = red[0]; __syncthreads();
    float c0 = 0.f, c1 = 0.f;
    for (int t = 0; t < 128; ++t) {
        float a = att[t];
        const float* er = u_enc + (size_t)t * 4096 + b * 512;
        c0 += a * er[tid];
        c1 += a * er[tid + 256];
    }
    float inv = 1.0f / S;
    ws[OFF_Y + b * 1024 + tid]       = c0 * inv;
    ws[OFF_Y + b * 1024 + tid + 256] = c1 * inv;
}

// K3b: gi = gru_bih + Wih @ [c_embed, context]  (wave per row, all 8 b)
__global__ __launch_bounds__(256) void k_gi(
    const float* __restrict__ gru_Wih, const float* __restrict__ gru_bih,
    float* __restrict__ ws)
{
    int lane = threadIdx.x & 63;
    int r = __builtin_amdgcn_readfirstlane(blockIdx.x * 4 + (threadIdx.x >> 6)); // 0..1535
    const float* wr = gru_Wih + (size_t)r * 1024;
    float4 w[4];
#pragma unroll
    for (int p = 0; p < 4; ++p)
        w[p] = *reinterpret_cast<const float4*>(wr + lane * 4 + p * 256);
    float acc[8];
#pragma unroll
    for (int b = 0; b < 8; ++b) {
        acc[b] = 0.f;
#pragma unroll
        for (int p = 0; p < 4; ++p) {
            int k = lane * 4 + p * 256;
            const float* xs = (p < 2) ? (ws + OFF_CEMB + b * 512 + k)
                                      : (ws + OFF_Y + b * 1024 + (k - 512));
            float4 x4 = *reinterpret_cast<const float4*>(xs);
            acc[b] += w[p].x*x4.x + w[p].y*x4.y + w[p].z*x4.z + w[p].w*x4.w;
        }
    }
#pragma unroll
    for (int b = 0; b < 8; ++b) acc[b] = wave_sum(acc[b]);
    if (lane == 0) {
        float bias = gru_bih[r];
#pragma unroll
        for (int b = 0; b < 8; ++b) ws[OFF_GI + b * 1536 + r] = acc[b] + bias;
    }
}

// K3c: GRU elementwise -> h_new ; pgen
__global__ __launch_bounds__(256) void k_gru(
    const float* __restrict__ last_h,
    const float* __restrict__ pgen_W, const float* __restrict__ pgen_b,
    float* __restrict__ ws, float* __restrict__ out)
{
    __shared__ float red[256];
    int b = blockIdx.x, tid = threadIdx.x;
    const float* gi = ws + OFF_GI + b * 1536;
    const float* gh = ws + OFF_GH + b * 1536;
    float pp = 0.f;
#pragma unroll
    for (int q = 0; q < 2; ++q) {
        int i = tid + q * 256;
        float r = 1.f / (1.f + expf(-(gi[i] + gh[i])));
        float z = 1.f / (1.f + expf(-(gi[512 + i] + gh[512 + i])));
        float n = tanhf(gi[1024 + i] + r * gh[1024 + i]);
        float h = last_h[b * 512 + i];
        float hn = (1.f - z) * n + z * h;
        ws[OFF_Y + b * 1024 + 512 + i] = hn;
        out[OUT_H1 + b * 512 + i] = hn;
        out[OUT_H2 + b * 512 + i] = hn;
        float cx = ws[OFF_Y + b * 1024 + i];
        float ce = ws[OFF_CEMB + b * 512 + i];
        pp += cx * pgen_W[i] + hn * pgen_W[512 + i] + ce * pgen_W[1024 + i];
    }
    red[tid] = pp; __syncthreads();
    for (int s = 128; s > 0; s >>= 1) {
        if (tid < s) red[tid] += red[tid + s];
        __syncthreads();
    }
    if (tid == 0) ws[OFF_PGEN + b] = 1.f / (1.f + expf(-(red[0] + pgen_b[0])));
}

// K4 (fused): blocks 0..255 copy-score MFMA GEMM; blocks 256..755 proj streaming.
// The MFMA tile is compute-bound, proj is HBM-bound -> they overlap on the CUs.
__global__ __launch_bounds__(256) void k_gemmproj(
    const float* __restrict__ henc, const unsigned short* __restrict__ wsplit,
    const float* __restrict__ c2b,
    const float* __restrict__ projW, const float* __restrict__ projb,
    float* __restrict__ ws, float* __restrict__ out)
{
    if (blockIdx.x < 256) {
        __shared__ short As[2][64][40];
        __shared__ short Ws[2][128][40];
        int rbase = (blockIdx.x >> 2) * 64;
        int j0    = (blockIdx.x & 3) * 128;
        mfma_tanh_body(henc, wsplit, wsplit + 262144,
                       c2b, 0, ws + OFF_Y + 512, 1024,
                       ws + OFF_SCORE, 512, rbase, j0, As, Ws);
    } else {
        int lane = threadIdx.x & 63;
        int gw = (blockIdx.x - 256) * 4 + (threadIdx.x >> 6);
        const int nw = 500 * 4;
        float4 yreg[8][4];
#pragma unroll
        for (int b = 0; b < 8; ++b)
#pragma unroll
            for (int p = 0; p < 4; ++p)
                yreg[b][p] = *reinterpret_cast<const float4*>(ws + OFF_Y + b * 1024 + p * 256 + lane * 4);

        for (int v = gw; v < VOC; v += nw) {
            const float4* wr = reinterpret_cast<const float4*>(projW + (size_t)v * 1024);
            float4 w0 = wr[lane], w1 = wr[64 + lane], w2 = wr[128 + lane], w3 = wr[192 + lane];
            float acc[8];
#pragma unroll
            for (int b = 0; b < 8; ++b) {
                acc[b] = w0.x*yreg[b][0].x + w0.y*yreg[b][0].y + w0.z*yreg[b][0].z + w0.w*yreg[b][0].w
                       + w1.x*yreg[b][1].x + w1.y*yreg[b][1].y + w1.z*yreg[b][1].z + w1.w*yreg[b][1].w
                       + w2.x*yreg[b][2].x + w2.y*yreg[b][2].y + w2.z*yreg[b][2].z + w2.w*yreg[b][2].w
                       + w3.x*yreg[b][3].x + w3.y*yreg[b][3].y + w3.z*yreg[b][3].z + w3.w*yreg[b][3].w;
            }
#pragma unroll
            for (int b = 0; b < 8; ++b) acc[b] = wave_sum(acc[b]);
            if (lane == 0) {
                float pb = projb[v];
#pragma unroll
                for (int b = 0; b < 8; ++b) out[b * WID_ + v] = acc[b] + pb;
            }
        }
    }
}

// K5: per-batch softmax over copy scores + sparse scatter of es into extra
__global__ __launch_bounds__(512) void k_copy_sm(
    const int* __restrict__ htok, float* __restrict__ ws)
{
    __shared__ float red[512];
    __shared__ float es[512];
    int b = blockIdx.x, t = threadIdx.x;
    float s = ws[OFF_SCORE + b * 512 + t];
    red[t] = s; __syncthreads();
    for (int st = 256; st > 0; st >>= 1) {
        if (t < st) red[t] = fmaxf(red[t], red[t + st]);
        __syncthreads();
    }
    float m = red[0]; __syncthreads();
    float e = expf(s - m);
    es[t] = e; red[t] = e; __syncthreads();
    for (int st = 256; st > 0; st >>= 1) {
        if (t < st) red[t] += red[t + st];
        __syncthreads();
    }
    if (t == 0) {
        ws[OFF_M + b]   = m;
        ws[OFF_EPS + b] = 1e-10f * red[0];
    }
    if (t < 511) {
        int tok = htok[t * 8 + b];
        int col = (tok == 2) ? (VOC + t) : tok;
        float val = (tok == 2) ? 5.0f : 1.0f;
        atomicAdd(ws + OFF_EXTRA + b * WID_ + col, (val - 1e-10f) * es[t + 1]);
    }
}

// K6: numerators (shifted-exp, no max pass) kept in VGPRs, block sum, scale, write
__global__ __launch_bounds__(1024) void k_final2(
    float* __restrict__ ws, float* __restrict__ out)
{
    __shared__ float red[1024];
    int b = blockIdx.x, tid = threadIdx.x;
    float gp   = ws[OFF_PGEN + b];
    float cq   = 1.f - gp;
    float m    = ws[OFF_M + b];
    float epsS = ws[OFF_EPS + b];
    float nums[32];
    float loc = 0.f;
    int cnt = 0;
    for (int w = tid; w < WID_; w += 1024, ++cnt) {
        float ex = ws[OFF_EXTRA + b * WID_ + w];
        float num = expf(cq * (logf(epsS + ex) + m) - SM_SHIFT);
        if (w < VOC) num += expf(gp * out[b * WID_ + w] - SM_SHIFT);
        nums[cnt] = num;
        loc += num;
    }
    red[tid] = loc; __syncthreads();
    for (int st = 512; st > 0; st >>= 1) {
        if (tid < st) red[tid] += red[tid + st];
        __syncthreads();
    }
    float inv = 1.f / red[0];
    cnt = 0;
    for (int w = tid; w < WID_; w += 1024, ++cnt)
        out[b * WID_ + w] = nums[cnt] * inv;
}

extern "C" void kernel_launch(void* const* d_in, const int* in_sizes, int n_in,
                              void* d_out, int out_size, void* d_ws, size_t ws_size,
                              hipStream_t stream)
{
    (void)in_sizes; (void)n_in; (void)out_size; (void)ws_size;
    const int*   htok  = (const int*)d_in[0];
    const float* henc  = (const float*)d_in[1];
    const float* uenc  = (const float*)d_in[2];
    const int*   ct    = (const int*)d_in[3];
    const float* lasth = (const float*)d_in[4];
    const float* embW  = (const float*)d_in[5];
    const float* attnW = (const float*)d_in[6];
    const float* attnb = (const float*)d_in[7];
    const float* attnv = (const float*)d_in[8];
    const float* gWih  = (const float*)d_in[9];
    const float* gWhh  = (const float*)d_in[10];
    const float* gbih  = (const float*)d_in[11];
    const float* gbhh  = (const float*)d_in[12];
    const float* projW = (const float*)d_in[13];
    const float* projb = (const float*)d_in[14];
    const float* c2W   = (const float*)d_in[15];
    const float* c2b   = (const float*)d_in[16];
    const float* pgW   = (const float*)d_in[17];
    const float* pgb   = (const float*)d_in[18];
    float* ws  = (float*)d_ws;
    float* out = (float*)d_out;
    unsigned short* wsplit = (unsigned short*)((char*)d_ws + OFF_WSPLIT_BYTES);

    // zero atomic-accumulation regions: LATT, SSUM, SCORE, EXTRA (contiguous)
    hipMemsetAsync((char*)d_ws + (size_t)OFF_LATT * 4, 0,
                   (size_t)(OFF_Y - OFF_LATT) * 4, stream);

    k_pre<<<1552, 256, 0, stream>>>(c2W, attnW, attnb, gWhh, gbhh, embW, ct, lasth,
                                    wsplit, ws);
    k_attgemm<<<dim3(16, 4), 256, 0, stream>>>(uenc, wsplit, attnv, ws);
    k_attn_ctx<<<8, 256, 0, stream>>>(uenc, ws);
    k_gi<<<384, 256, 0, stream>>>(gWih, gbih, ws);
    k_gru<<<8, 256, 0, stream>>>(lasth, pgW, pgb, ws, out);
    k_gemmproj<<<756, 256, 0, stream>>>(henc, wsplit, c2b, projW, projb, ws, out);
    k_copy_sm<<<8, 512, 0, stream>>>(htok, ws);
    k_final2<<<8, 1024, 0, stream>>>(ws, out);
}